// Round 1
// baseline (26.397 us; speedup 1.0000x reference)
//
#include <hip/hip_runtime.h>

// GradientFusionloss: loss = mean(|grad(gen_y) - max(grad(vis_y), grad(ir))|)
// grad(I) = |sobel_x(I)| + |sobel_y(I)|, zero-padded 3x3 cross-correlation.
// Shapes: vis (32,3,512,512) f32, ir (32,1,512,512) f32, gen (32,3,512,512) f32.
// Only channel 0 of vis/gen is used. Output: 1 fp32 scalar.

#define IMG_H 512
#define IMG_W 512
#define BATCH 32
#define ROWS 8                 // rows per thread strip
#define XT (IMG_W / 4)         // 128 x-tiles (4 px each)
#define STRIPS (IMG_H / ROWS)  // 64
#define THREADS 256
#define TOTAL_THREADS (BATCH * STRIPS * XT)     // 262144
#define NBLOCKS (TOTAL_THREADS / THREADS)       // 1024
#define NPIX ((double)BATCH * IMG_H * IMG_W)

struct Row { float l, x, y, z, w, r; };

__device__ __forceinline__ void zero_row(Row& r) {
    r.l = r.x = r.y = r.z = r.w = r.r = 0.0f;
}

__device__ __forceinline__ void load_row(const float* __restrict__ p, int xb,
                                         bool hl, bool hr, Row& r) {
    float4 v = *reinterpret_cast<const float4*>(p + xb);
    r.x = v.x; r.y = v.y; r.z = v.z; r.w = v.w;
    r.l = hl ? p[xb - 1] : 0.0f;
    r.r = hr ? p[xb + 4] : 0.0f;
}

// element j of the 6-wide register row, j in [-1, 4]; j is compile-time
__device__ __forceinline__ float gete(const Row& r, int j) {
    switch (j) {
        case -1: return r.l;
        case 0:  return r.x;
        case 1:  return r.y;
        case 2:  return r.z;
        case 3:  return r.w;
        default: return r.r;
    }
}

// |sobel_x| + |sobel_y| at column j of the 4-wide tile (XLA conv = correlation)
__device__ __forceinline__ float sobel_grad(const Row& t, const Row& m, const Row& b, int j) {
    float a  = gete(t, j - 1), bb = gete(t, j), c  = gete(t, j + 1);
    float d  = gete(m, j - 1),                  f  = gete(m, j + 1);
    float g  = gete(b, j - 1), hh = gete(b, j), i2 = gete(b, j + 1);
    float gx = (c - a) + 2.0f * (f - d) + (i2 - g);
    float gy = (a + 2.0f * bb + c) - (g + 2.0f * hh + i2);
    return fabsf(gx) + fabsf(gy);
}

__global__ __launch_bounds__(THREADS)
void grad_loss_kernel(const float* __restrict__ vis, const float* __restrict__ ir,
                      const float* __restrict__ gen, float* __restrict__ partial) {
    int t    = blockIdx.x * THREADS + threadIdx.x;
    int xt   = t & (XT - 1);
    int rest = t >> 7;
    int ys   = rest & (STRIPS - 1);
    int b    = rest >> 6;

    const float* pv = vis + (size_t)b * 3 * IMG_H * IMG_W;  // channel 0
    const float* pi = ir  + (size_t)b * IMG_H * IMG_W;
    const float* pg = gen + (size_t)b * 3 * IMG_H * IMG_W;  // channel 0

    int  xb = xt * 4;
    bool hl = (xt != 0), hr = (xt != XT - 1);
    int  y0 = ys * ROWS;

    Row v0, v1, v2, i0, i1, i2r, g0, g1, g2;
    if (y0 == 0) {
        zero_row(v0); zero_row(i0); zero_row(g0);
    } else {
        load_row(pv + (size_t)(y0 - 1) * IMG_W, xb, hl, hr, v0);
        load_row(pi + (size_t)(y0 - 1) * IMG_W, xb, hl, hr, i0);
        load_row(pg + (size_t)(y0 - 1) * IMG_W, xb, hl, hr, g0);
    }
    load_row(pv + (size_t)y0 * IMG_W, xb, hl, hr, v1);
    load_row(pi + (size_t)y0 * IMG_W, xb, hl, hr, i1);
    load_row(pg + (size_t)y0 * IMG_W, xb, hl, hr, g1);

    float acc = 0.0f;
    #pragma unroll
    for (int r = 0; r < ROWS; ++r) {
        int y = y0 + r;
        if (y == IMG_H - 1) {   // wave-uniform (xt varies, ys uniform per wave)
            zero_row(v2); zero_row(i2r); zero_row(g2);
        } else {
            load_row(pv + (size_t)(y + 1) * IMG_W, xb, hl, hr, v2);
            load_row(pi + (size_t)(y + 1) * IMG_W, xb, hl, hr, i2r);
            load_row(pg + (size_t)(y + 1) * IMG_W, xb, hl, hr, g2);
        }
        #pragma unroll
        for (int j = 0; j < 4; ++j) {
            float ggen = sobel_grad(g0, g1, g2, j);
            float gvis = sobel_grad(v0, v1, v2, j);
            float gir  = sobel_grad(i0, i1, i2r, j);
            acc += fabsf(ggen - fmaxf(gvis, gir));
        }
        v0 = v1; v1 = v2;
        i0 = i1; i1 = i2r;
        g0 = g1; g1 = g2;
    }

    // block reduction (deterministic)
    #pragma unroll
    for (int off = 32; off > 0; off >>= 1)
        acc += __shfl_down(acc, off, 64);
    __shared__ float s[THREADS / 64];
    int lane = threadIdx.x & 63, wid = threadIdx.x >> 6;
    if (lane == 0) s[wid] = acc;
    __syncthreads();
    if (threadIdx.x == 0)
        partial[blockIdx.x] = s[0] + s[1] + s[2] + s[3];
}

__global__ __launch_bounds__(THREADS)
void reduce_kernel(const float* __restrict__ partial, float* __restrict__ out) {
    float acc = 0.0f;
    for (int i = threadIdx.x; i < NBLOCKS; i += THREADS)
        acc += partial[i];
    #pragma unroll
    for (int off = 32; off > 0; off >>= 1)
        acc += __shfl_down(acc, off, 64);
    __shared__ float s[THREADS / 64];
    int lane = threadIdx.x & 63, wid = threadIdx.x >> 6;
    if (lane == 0) s[wid] = acc;
    __syncthreads();
    if (threadIdx.x == 0)
        out[0] = (float)((s[0] + s[1] + s[2] + s[3]) * (1.0 / NPIX));
}

extern "C" void kernel_launch(void* const* d_in, const int* in_sizes, int n_in,
                              void* d_out, int out_size, void* d_ws, size_t ws_size,
                              hipStream_t stream) {
    const float* vis = (const float*)d_in[0];
    const float* ir  = (const float*)d_in[1];
    const float* gen = (const float*)d_in[2];
    float* out       = (float*)d_out;
    float* partial   = (float*)d_ws;   // NBLOCKS floats = 4 KiB

    grad_loss_kernel<<<NBLOCKS, THREADS, 0, stream>>>(vis, ir, gen, partial);
    reduce_kernel<<<1, THREADS, 0, stream>>>(partial, out);
}